// Round 1
// baseline (123.198 us; speedup 1.0000x reference)
//
#include <hip/hip_runtime.h>
#include <hip/hip_bf16.h>

// Problem constants (from setup_inputs): B=8, N=M=4096, 3D points, fp32.
constexpr int B_ = 8;
constexpr int N_ = 4096;
constexpr int M_ = 4096;
constexpr int TPB = 256;        // threads per block (4 waves)
constexpr int SPLIT = 8;        // y-direction chunks per (b, x-block)
constexpr int CHUNK = M_ / SPLIT;   // 512 database points staged in LDS
constexpr int XBLKS = N_ / TPB;     // 16 x-blocks per batch

// Pass 1: for each query point, min squared distance over one database chunk,
// combined across chunks with atomicMin on the float bit pattern (valid for
// non-negative floats). dir=0: X->Y, dir=1: Y->X. Deterministic (min is
// order-independent) so graph replay is safe.
__global__ __launch_bounds__(TPB) void chamfer_pass1(
    const float* __restrict__ X, const float* __restrict__ Yp,
    float* __restrict__ minx, float* __restrict__ miny)
{
    __shared__ float4 sdb[CHUNK];   // xyz + ||y||^2  (aligned 16B reads)

    int bid = blockIdx.x;
    const int dir   = bid & 1;            bid >>= 1;
    const int chunk = bid & (SPLIT - 1);  bid >>= 3;
    const int xblk  = bid & (XBLKS - 1);
    const int b     = bid >> 4;

    const float* q   = dir ? Yp : X;
    const float* db  = dir ? X  : Yp;
    float* outmin    = dir ? miny : minx;

    // Stage this database chunk into LDS (xyz + norm).
    const int dbbase = b * M_ + chunk * CHUNK;
    for (int p = threadIdx.x; p < CHUNK; p += TPB) {
        const float* src = db + (size_t)(dbbase + p) * 3;
        float a0 = src[0], a1 = src[1], a2 = src[2];
        sdb[p] = make_float4(a0, a1, a2, a0 * a0 + a1 * a1 + a2 * a2);
    }
    __syncthreads();

    // One query point per thread.
    const int qi = b * N_ + xblk * TPB + threadIdx.x;
    const float* qp = q + (size_t)qi * 3;
    const float x0 = qp[0], x1 = qp[1], x2 = qp[2];
    const float xn = x0 * x0 + x1 * x1 + x2 * x2;

    // Track min of (||y||^2 - 2 x.y); add ||x||^2 after the loop.
    const float BIG = 3.0e38f;
    float m0 = BIG, m1 = BIG, m2 = BIG, m3 = BIG;
    #pragma unroll 4
    for (int j = 0; j < CHUNK; j += 4) {
        float4 p0 = sdb[j + 0];
        float4 p1 = sdb[j + 1];
        float4 p2 = sdb[j + 2];
        float4 p3 = sdb[j + 3];
        float d0 = fmaf(x0, p0.x, fmaf(x1, p0.y, x2 * p0.z));
        float d1 = fmaf(x0, p1.x, fmaf(x1, p1.y, x2 * p1.z));
        float d2 = fmaf(x0, p2.x, fmaf(x1, p2.y, x2 * p2.z));
        float d3 = fmaf(x0, p3.x, fmaf(x1, p3.y, x2 * p3.z));
        float v0 = fmaf(-2.0f, d0, p0.w);
        float v1 = fmaf(-2.0f, d1, p1.w);
        float v2 = fmaf(-2.0f, d2, p2.w);
        float v3 = fmaf(-2.0f, d3, p3.w);
        m0 = fminf(m0, v0);
        m1 = fminf(m1, v1);
        m2 = fminf(m2, v2);
        m3 = fminf(m3, v3);
    }
    float mm = fminf(fminf(m0, m1), fminf(m2, m3));
    float d2min = fmaxf(mm + xn, 0.0f);   // clamp (also keeps int-order valid)
    atomicMin((int*)&outmin[qi], __float_as_int(d2min));
}

// Pass 2: single block. Sum sqrt of all 64K min-d2 entries (both directions
// share the scale 1/(B*N) since N==M), compute the registration loss on
// lanes 0..7, emit (total, L_R, L_CD).
__global__ __launch_bounds__(1024) void finalize_kernel(
    const float* __restrict__ minx,   // B*N
    const float* __restrict__ miny,   // B*M
    const float* __restrict__ R,  const float* __restrict__ t,
    const float* __restrict__ S,  const float* __restrict__ Rg,
    const float* __restrict__ tg, const float* __restrict__ Sg,
    float* __restrict__ out)
{
    __shared__ float wsum[16];
    __shared__ float sreg[8];
    const int tid = threadIdx.x;

    float s = 0.0f;
    const int total = B_ * N_ + B_ * M_;
    for (int i = tid; i < total; i += 1024) {
        float v = (i < B_ * N_) ? minx[i] : miny[i - B_ * N_];
        s += sqrtf(v);
    }
    // wave(64) shuffle reduce
    #pragma unroll
    for (int off = 32; off > 0; off >>= 1) s += __shfl_down(s, off, 64);
    if ((tid & 63) == 0) wsum[tid >> 6] = s;

    if (tid < 8) {
        // registration loss for batch `tid`
        const float* Rb  = R  + tid * 9;
        const float* Rgb = Rg + tid * 9;
        float acc = 0.0f;
        #pragma unroll
        for (int i = 0; i < 3; ++i) {
            #pragma unroll
            for (int k = 0; k < 3; ++k) {
                float v = 0.0f;
                #pragma unroll
                for (int j = 0; j < 3; ++j)
                    v = fmaf(Rgb[j * 3 + i], Rb[j * 3 + k], v);  // (R_g^T R)[i][k]
                if (i == k) v -= 1.0f;
                acc = fmaf(v, v, acc);
            }
        }
        #pragma unroll
        for (int d = 0; d < 3; ++d) {
            float dv = tg[tid * 3 + d] - t[tid * 3 + d];
            acc = fmaf(dv, dv, acc);
        }
        float dS = Sg[tid] - S[tid];
        acc = fmaf(dS, dS, acc);
        sreg[tid] = acc;
    }
    __syncthreads();

    if (tid == 0) {
        float tot = 0.0f;
        #pragma unroll
        for (int w = 0; w < 16; ++w) tot += wsum[w];
        float L_CD = tot / (float)(B_ * N_);   // == sum/(B*N) + sum/(B*M), N==M
        float rs = 0.0f;
        #pragma unroll
        for (int b = 0; b < 8; ++b) rs += sreg[b];
        float L_R = rs / (float)B_;
        out[0] = L_R + L_CD;
        out[1] = L_R;
        out[2] = L_CD;
    }
}

extern "C" void kernel_launch(void* const* d_in, const int* in_sizes, int n_in,
                              void* d_out, int out_size, void* d_ws, size_t ws_size,
                              hipStream_t stream) {
    const float* R  = (const float*)d_in[0];
    const float* t  = (const float*)d_in[1];
    const float* S  = (const float*)d_in[2];
    const float* Rg = (const float*)d_in[3];
    const float* tg = (const float*)d_in[4];
    const float* Sg = (const float*)d_in[5];
    const float* X  = (const float*)d_in[6];   // T_X [B,N,3]
    const float* Yp = (const float*)d_in[7];   // Y   [B,M,3]
    float* out = (float*)d_out;

    float* minx = (float*)d_ws;            // B*N floats
    float* miny = minx + (size_t)B_ * N_;  // B*M floats

    // Init min arrays to a huge positive float: 0x7f7f7f7f ~= 3.39e38.
    hipMemsetAsync(d_ws, 0x7f, (size_t)(B_ * N_ + B_ * M_) * sizeof(float), stream);

    chamfer_pass1<<<2 * B_ * XBLKS * SPLIT, TPB, 0, stream>>>(X, Yp, minx, miny);
    finalize_kernel<<<1, 1024, 0, stream>>>(minx, miny, R, t, S, Rg, tg, Sg, out);
}

// Round 2
// 93.095 us; speedup vs baseline: 1.3234x; 1.3234x over previous
//
#include <hip/hip_runtime.h>
#include <hip/hip_bf16.h>

// Problem constants (from setup_inputs): B=8, N=M=4096, 3D points, fp32.
constexpr int B_ = 8;
constexpr int N_ = 4096;
constexpr int M_ = 4096;
constexpr int TPB = 256;            // threads per block (4 waves)
constexpr int QPT = 2;              // queries per thread
constexpr int QPB = TPB * QPT;      // 512 queries per block
constexpr int QBLKS = N_ / QPB;     // 8 query-blocks per batch
constexpr int SPLIT = 8;            // db chunks per query
constexpr int CHUNK = M_ / SPLIT;   // 512 db points staged in LDS

// ---------------------------------------------------------------------------
// K1: per-(dir, batch, query-block, chunk) partial min of squared distance.
// LDS holds the chunk pre-scaled as (-2x, -2y, -2z, ||y||^2) so each pair is
// a pure 3-FMA chain + 1 min (4 VALU ops/pair). Each thread owns 2 queries so
// one broadcast ds_read_b128 feeds 8 VALU ops. Chunks combine via atomicMin
// on the float bit pattern (valid & order-independent for non-negative f32).
// ---------------------------------------------------------------------------
__global__ __launch_bounds__(TPB) void chamfer_pass1(
    const float* __restrict__ X, const float* __restrict__ Yp,
    float* __restrict__ minx, float* __restrict__ miny)
{
    __shared__ float4 sdb[CHUNK];   // 8 KB

    int bid = blockIdx.x;
    const int dir   = bid & 1;            bid >>= 1;
    const int chunk = bid & (SPLIT - 1);  bid >>= 3;
    const int qblk  = bid & (QBLKS - 1);
    const int b     = bid >> 3;

    const float* q  = dir ? Yp : X;
    const float* db = dir ? X  : Yp;
    float* outmin   = dir ? miny : minx;

    // Stage chunk into LDS, pre-scaled.
    const int dbbase = b * M_ + chunk * CHUNK;
    for (int p = threadIdx.x; p < CHUNK; p += TPB) {
        const float* src = db + (size_t)(dbbase + p) * 3;
        float a0 = src[0], a1 = src[1], a2 = src[2];
        sdb[p] = make_float4(-2.0f * a0, -2.0f * a1, -2.0f * a2,
                             a0 * a0 + a1 * a1 + a2 * a2);
    }
    __syncthreads();

    // Two query points per thread (n0, n0+TPB keeps loads coalesced).
    const int n0 = qblk * QPB + threadIdx.x;
    const int n1 = n0 + TPB;
    const float* qp0 = q + (size_t)(b * N_ + n0) * 3;
    const float* qp1 = q + (size_t)(b * N_ + n1) * 3;
    const float ax = qp0[0], ay = qp0[1], az = qp0[2];
    const float bx = qp1[0], by = qp1[1], bz = qp1[2];
    const float an = ax * ax + ay * ay + az * az;
    const float bn = bx * bx + by * by + bz * bz;

    const float BIG = 3.0e38f;
    float m0a = BIG, m0b = BIG, m1a = BIG, m1b = BIG;
    #pragma unroll 4
    for (int j = 0; j < CHUNK; j += 4) {
        float4 p0 = sdb[j + 0];
        float4 p1 = sdb[j + 1];
        float4 p2 = sdb[j + 2];
        float4 p3 = sdb[j + 3];
        // q0 against 4 points
        float v00 = fmaf(ax, p0.x, fmaf(ay, p0.y, fmaf(az, p0.z, p0.w)));
        float v01 = fmaf(ax, p1.x, fmaf(ay, p1.y, fmaf(az, p1.z, p1.w)));
        float v02 = fmaf(ax, p2.x, fmaf(ay, p2.y, fmaf(az, p2.z, p2.w)));
        float v03 = fmaf(ax, p3.x, fmaf(ay, p3.y, fmaf(az, p3.z, p3.w)));
        m0a = fminf(m0a, v00);
        m0b = fminf(m0b, v01);
        m0a = fminf(m0a, v02);
        m0b = fminf(m0b, v03);
        // q1 against the same 4 points
        float v10 = fmaf(bx, p0.x, fmaf(by, p0.y, fmaf(bz, p0.z, p0.w)));
        float v11 = fmaf(bx, p1.x, fmaf(by, p1.y, fmaf(bz, p1.z, p1.w)));
        float v12 = fmaf(bx, p2.x, fmaf(by, p2.y, fmaf(bz, p2.z, p2.w)));
        float v13 = fmaf(bx, p3.x, fmaf(by, p3.y, fmaf(bz, p3.z, p3.w)));
        m1a = fminf(m1a, v10);
        m1b = fminf(m1b, v11);
        m1a = fminf(m1a, v12);
        m1b = fminf(m1b, v13);
    }
    float d0 = fmaxf(fminf(m0a, m0b) + an, 0.0f);
    float d1 = fmaxf(fminf(m1a, m1b) + bn, 0.0f);
    atomicMin((int*)&outmin[b * N_ + n0], __float_as_int(d0));
    atomicMin((int*)&outmin[b * N_ + n1], __float_as_int(d1));
}

// ---------------------------------------------------------------------------
// K2: parallel sqrt + sum. 256 blocks x 256 threads cover all 64K min-d2
// entries; deterministic intra-block tree reduction; one partial per block.
// ---------------------------------------------------------------------------
__global__ __launch_bounds__(TPB) void sqrt_sum_kernel(
    const float* __restrict__ mins,   // minx followed by miny, 2*B*N entries
    float* __restrict__ bsum)
{
    __shared__ float wsum[4];
    const int i = blockIdx.x * TPB + threadIdx.x;
    float s = sqrtf(mins[i]);
    #pragma unroll
    for (int off = 32; off > 0; off >>= 1) s += __shfl_down(s, off, 64);
    if ((threadIdx.x & 63) == 0) wsum[threadIdx.x >> 6] = s;
    __syncthreads();
    if (threadIdx.x == 0)
        bsum[blockIdx.x] = wsum[0] + wsum[1] + wsum[2] + wsum[3];
}

// ---------------------------------------------------------------------------
// K3: one small block. Sum the 256 block partials, compute the registration
// loss (8 batches on threads 0..7), write (total, L_R, L_CD).
// ---------------------------------------------------------------------------
__global__ __launch_bounds__(TPB) void final_kernel(
    const float* __restrict__ bsum,
    const float* __restrict__ R,  const float* __restrict__ t,
    const float* __restrict__ S,  const float* __restrict__ Rg,
    const float* __restrict__ tg, const float* __restrict__ Sg,
    float* __restrict__ out)
{
    __shared__ float wsum[4];
    __shared__ float sreg[8];
    const int tid = threadIdx.x;

    float s = bsum[tid];
    #pragma unroll
    for (int off = 32; off > 0; off >>= 1) s += __shfl_down(s, off, 64);
    if ((tid & 63) == 0) wsum[tid >> 6] = s;

    if (tid < 8) {
        const float* Rb  = R  + tid * 9;
        const float* Rgb = Rg + tid * 9;
        float acc = 0.0f;
        #pragma unroll
        for (int i = 0; i < 3; ++i) {
            #pragma unroll
            for (int k = 0; k < 3; ++k) {
                float v = 0.0f;
                #pragma unroll
                for (int j = 0; j < 3; ++j)
                    v = fmaf(Rgb[j * 3 + i], Rb[j * 3 + k], v);  // (R_g^T R)[i][k]
                if (i == k) v -= 1.0f;
                acc = fmaf(v, v, acc);
            }
        }
        #pragma unroll
        for (int d = 0; d < 3; ++d) {
            float dv = tg[tid * 3 + d] - t[tid * 3 + d];
            acc = fmaf(dv, dv, acc);
        }
        float dS = Sg[tid] - S[tid];
        acc = fmaf(dS, dS, acc);
        sreg[tid] = acc;
    }
    __syncthreads();

    if (tid == 0) {
        float tot = wsum[0] + wsum[1] + wsum[2] + wsum[3];
        float L_CD = tot / (float)(B_ * N_);   // sum/(B*N) + sum/(B*M), N==M
        float rs = 0.0f;
        #pragma unroll
        for (int bb = 0; bb < 8; ++bb) rs += sreg[bb];
        float L_R = rs / (float)B_;
        out[0] = L_R + L_CD;
        out[1] = L_R;
        out[2] = L_CD;
    }
}

extern "C" void kernel_launch(void* const* d_in, const int* in_sizes, int n_in,
                              void* d_out, int out_size, void* d_ws, size_t ws_size,
                              hipStream_t stream) {
    const float* R  = (const float*)d_in[0];
    const float* t  = (const float*)d_in[1];
    const float* S  = (const float*)d_in[2];
    const float* Rg = (const float*)d_in[3];
    const float* tg = (const float*)d_in[4];
    const float* Sg = (const float*)d_in[5];
    const float* X  = (const float*)d_in[6];   // T_X [B,N,3]
    const float* Yp = (const float*)d_in[7];   // Y   [B,M,3]
    float* out = (float*)d_out;

    float* minx = (float*)d_ws;                 // B*N floats
    float* miny = minx + (size_t)B_ * N_;       // B*M floats
    float* bsum = miny + (size_t)B_ * M_;       // 256 floats

    // Init min arrays to a huge positive float: 0x7f7f7f7f ~= 3.39e38.
    hipMemsetAsync(d_ws, 0x7f, (size_t)(B_ * N_ + B_ * M_) * sizeof(float), stream);

    chamfer_pass1<<<2 * B_ * QBLKS * SPLIT, TPB, 0, stream>>>(X, Yp, minx, miny);
    sqrt_sum_kernel<<<(2 * B_ * N_) / TPB, TPB, 0, stream>>>(minx, bsum);
    final_kernel<<<1, TPB, 0, stream>>>(bsum, R, t, S, Rg, tg, Sg, out);
}